// Round 14
// baseline (177.123 us; speedup 1.0000x reference)
//
#include <hip/hip_runtime.h>
#include <hip/hip_bf16.h>

#define B 4
#define S 2048
#define D 512
#define P 16
#define NC 64   // chunks over sequence
#define CL 32   // chunk length = S/NC
#define REP 8   // attribution probe: repeat each kernel body 8x

// opaque zero in an SGPR: blocks cross-rep CSE but PRESERVES uniform
// (scalarizable) addressing — the R11 probe's v_mov version broke it.
__device__ __forceinline__ int opaque_zero_s() {
    int z;
    asm volatile("s_mov_b32 %0, 0" : "=s"(z));
    return z;
}

// ---------------------------------------------------------------------------
// Kernel 1 (R10/R13 body x REP): prods + softmax.
// ---------------------------------------------------------------------------
__global__ __launch_bounds__(256) void k_prods(const float* __restrict__ x,
                                               const float* __restrict__ proxy,
                                               float* __restrict__ prods,
                                               float* __restrict__ wgt) {
    const int wave = (blockIdx.x * blockDim.x + threadIdx.x) >> 6;
    const int lane = threadIdx.x & 63;
    const int bs0  = wave * 4;

#pragma unroll 1
    for (int rep = 0; rep < REP; ++rep) {
        const int z = opaque_zero_s();
        const float* xz = x + z;
        const float* pz = proxy + z;

        float4 pA[P], pB[P];
#pragma unroll
        for (int p = 0; p < P; ++p) {
            const float* pr = pz + p * D + lane * 8;
            pA[p] = *(const float4*)pr;
            pB[p] = *(const float4*)(pr + 4);
        }

#pragma unroll
        for (int r = 0; r < 4; ++r) {
            const int bs = bs0 + r;
            const float* xr = xz + (size_t)bs * D + lane * 8;
            float4 xa = *(const float4*)xr;
            float4 xb = *(const float4*)(xr + 4);

            float part[P];
#pragma unroll
            for (int p = 0; p < P; ++p) {
                part[p] = xa.x*pA[p].x + xa.y*pA[p].y + xa.z*pA[p].z + xa.w*pA[p].w
                        + xb.x*pB[p].x + xb.y*pB[p].y + xb.z*pB[p].z + xb.w*pB[p].w;
            }

            float a8[8];
#pragma unroll
            for (int k = 0; k < 8; ++k) {
                bool hi = lane & 1;
                float mine = hi ? part[2*k+1] : part[2*k];
                float oth  = hi ? part[2*k]   : part[2*k+1];
                a8[k] = mine + __shfl_xor(oth, 1);
            }
            float a4[4];
#pragma unroll
            for (int k = 0; k < 4; ++k) {
                bool hi = lane & 2;
                float mine = hi ? a8[2*k+1] : a8[2*k];
                float oth  = hi ? a8[2*k]   : a8[2*k+1];
                a4[k] = mine + __shfl_xor(oth, 2);
            }
            float a2[2];
#pragma unroll
            for (int k = 0; k < 2; ++k) {
                bool hi = lane & 4;
                float mine = hi ? a4[2*k+1] : a4[2*k];
                float oth  = hi ? a4[2*k]   : a4[2*k+1];
                a2[k] = mine + __shfl_xor(oth, 4);
            }
            float a1;
            {
                bool hi = lane & 8;
                float mine = hi ? a2[1] : a2[0];
                float oth  = hi ? a2[0] : a2[1];
                a1 = mine + __shfl_xor(oth, 8);
            }
            a1 += __shfl_xor(a1, 16);
            a1 += __shfl_xor(a1, 32);

            float m = a1;
#pragma unroll
            for (int off = 1; off < 16; off <<= 1) m = fmaxf(m, __shfl_xor(m, off));
            float e = __expf((a1 - m) * 0.25f);
            float den = e;
#pragma unroll
            for (int off = 1; off < 16; off <<= 1) den += __shfl_xor(den, off);

            if (lane < P) {
                prods[(size_t)bs * P + lane] = a1;
                wgt  [(size_t)bs * P + lane] = e / den;
            }
        }
    }
}

// ---------------------------------------------------------------------------
// Kernel 2 (R13 body x REP): chunk totals. Scalarized prods loads preserved.
// ---------------------------------------------------------------------------
__global__ __launch_bounds__(256) void k_totals(const float* __restrict__ x,
                                                const float* __restrict__ prods,
                                                float* __restrict__ T) {
    int h = blockIdx.x & 1;
    int c = (blockIdx.x >> 1) & (NC - 1);
    int b = blockIdx.x >> 7;
    int d = h * 256 + threadIdx.x;
    int bs0 = b * S + c * CL;

#pragma unroll 1
    for (int rep = 0; rep < REP; ++rep) {
        const int z = opaque_zero_s();
        const float* xb = x + z;
        const float* pb = prods + z;

        float acc[P];
#pragma unroll
        for (int p = 0; p < P; ++p) acc[p] = 0.f;

#pragma unroll 4
        for (int i = 0; i < CL; ++i) {
            int bs = bs0 + i;
            float xv = xb[(size_t)bs * D + d];
            const float4* pp = (const float4*)(pb + (size_t)bs * P);
            float pr[P];
            ((float4*)pr)[0] = pp[0];
            ((float4*)pr)[1] = pp[1];
            ((float4*)pr)[2] = pp[2];
            ((float4*)pr)[3] = pp[3];
#pragma unroll
            for (int p = 0; p < P; ++p) acc[p] = fmaf(pr[p], xv, acc[p]);
        }
        size_t tb = ((size_t)(b * NC + c)) * (P * D) + d;
#pragma unroll
        for (int p = 0; p < P; ++p) T[tb + p * D] = acc[p];
    }
}

// ---------------------------------------------------------------------------
// Kernel 3 (R13 body x REP): exclusive prefix. Reps 0..REP-2 -> T2 scratch,
// final rep in place (same final state as R13).
// ---------------------------------------------------------------------------
__global__ __launch_bounds__(256) void k_scan(float* __restrict__ T,
                                              float* __restrict__ T2) {
    int t = blockIdx.x * blockDim.x + threadIdx.x;
    int d = t & (D - 1);
    int p = (t >> 9) & (P - 1);
    int b = t >> 13;
    size_t base = ((size_t)b * NC * P + p) * D + d;

#pragma unroll 1
    for (int rep = 0; rep < REP; ++rep) {
        const int z = opaque_zero_s();
        const float* src = T + z;
        float* dst = (rep == REP - 1) ? T : T2;
        float run = 0.f;
#pragma unroll 8
        for (int c = 0; c < NC; ++c) {
            size_t idx = base + (size_t)c * (P * D);
            float v = src[idx];
            dst[idx] = run;
            run += v;
        }
    }
}

// ---------------------------------------------------------------------------
// Kernel 4 (R13 body x REP): apply with LDS-staged prods/wgt + xv preload.
// ---------------------------------------------------------------------------
__global__ __launch_bounds__(256) void k_apply(const float* __restrict__ x,
                                               const float* __restrict__ prods,
                                               const float* __restrict__ wgt,
                                               const float* __restrict__ T,
                                               float* __restrict__ out) {
    __shared__ float s_pw[2][CL][P];

    int h = blockIdx.x & 1;
    int c = (blockIdx.x >> 1) & (NC - 1);
    int b = blockIdx.x >> 7;
    int d = h * 256 + threadIdx.x;
    int bs0 = b * S + c * CL;

#pragma unroll 1
    for (int rep = 0; rep < REP; ++rep) {
        const int z = opaque_zero_s();
        const float* xb = x + z;
        const float* pb = prods + z;
        const float* wb = wgt + z;

        {
            int t = threadIdx.x;
            if (t < 128) {
                ((float4*)&s_pw[0][0][0])[t] =
                    ((const float4*)(pb + (size_t)bs0 * P))[t];
            } else {
                ((float4*)&s_pw[1][0][0])[t - 128] =
                    ((const float4*)(wb + (size_t)bs0 * P))[t - 128];
            }
        }

        float xv[CL];
#pragma unroll
        for (int i = 0; i < CL; ++i) xv[i] = xb[(size_t)(bs0 + i) * D + d];

        float st[P];
        size_t tb = ((size_t)(b * NC + c)) * (P * D) + d;
#pragma unroll
        for (int p = 0; p < P; ++p) st[p] = T[tb + p * D];

        __syncthreads();

#pragma unroll
        for (int i = 0; i < CL; ++i) {
            float pr[P], ww[P];
            const float4* sp = (const float4*)&s_pw[0][i][0];
            const float4* sw = (const float4*)&s_pw[1][i][0];
            ((float4*)pr)[0] = sp[0];
            ((float4*)pr)[1] = sp[1];
            ((float4*)pr)[2] = sp[2];
            ((float4*)pr)[3] = sp[3];
            ((float4*)ww)[0] = sw[0];
            ((float4*)ww)[1] = sw[1];
            ((float4*)ww)[2] = sw[2];
            ((float4*)ww)[3] = sw[3];
            float o = 0.f;
#pragma unroll
            for (int p = 0; p < P; ++p) {
                st[p] = fmaf(pr[p], xv[i], st[p]);
                o = fmaf(ww[p], st[p], o);
            }
            out[(size_t)(bs0 + i) * D + d] = o;
        }
        __syncthreads();   // WAR guard before next rep re-stages s_pw
    }
}

extern "C" void kernel_launch(void* const* d_in, const int* in_sizes, int n_in,
                              void* d_out, int out_size, void* d_ws, size_t ws_size,
                              hipStream_t stream) {
    const float* x     = (const float*)d_in[0];
    const float* proxy = (const float*)d_in[1];
    float* out   = (float*)d_out;

    float* prods = (float*)d_ws;                 // 512 KiB
    float* wgt   = prods + (size_t)B * S * P;    // 512 KiB
    float* T     = wgt   + (size_t)B * S * P;    // 8 MiB
    float* T2    = T     + (size_t)B * NC * P * D; // 8 MiB probe scratch

    k_prods <<<(B * S) / 16,      256, 0, stream>>>(x, proxy, prods, wgt);
    k_totals<<<B * NC * 2,        256, 0, stream>>>(x, prods, T);
    k_scan  <<<(B * P * D) / 256, 256, 0, stream>>>(T, T2);
    k_apply <<<B * NC * 2,        256, 0, stream>>>(x, prods, wgt, T, out);
}

// Round 15
// 36.006 us; speedup vs baseline: 4.9192x; 4.9192x over previous
//
#include <hip/hip_runtime.h>
#include <hip/hip_bf16.h>

#define B 4
#define S 2048
#define D 512
#define P 16
#define NC 64   // chunks over sequence
#define CL 32   // chunk length = S/NC

// ---------------------------------------------------------------------------
// K1: fused prods+softmax+totals. Block = (b,c), 512 threads.
// Phase A (R10-verbatim per-wave body): wave wv owns rows 4wv..4wv+3; proxy
//   hoisted to VGPRs; merge-tree reduce; results -> LDS (for phase B) AND
//   global (for k_apply).
// Phase B (R13-apply-style): thread = d; xv[32] register preload; weights
//   read as uniform-address LDS float4 broadcasts (conflict-free, no SGPR
//   pressure — the R6 de-scalarization trap is bypassed).
// ---------------------------------------------------------------------------
__global__ __launch_bounds__(512) void k_pt(const float* __restrict__ x,
                                            const float* __restrict__ proxy,
                                            float* __restrict__ prods,
                                            float* __restrict__ wgt,
                                            float* __restrict__ T) {
    __shared__ float s_pr[CL][P];
    __shared__ float s_w [CL][P];

    const int c    = blockIdx.x & (NC - 1);
    const int b    = blockIdx.x >> 6;
    const int tid  = threadIdx.x;
    const int lane = tid & 63;
    const int wv   = tid >> 6;          // 0..7
    const int bs0  = b * S + c * CL;

    // ---------------- Phase A (R10 k_prods body for 4 rows)
    {
        float4 pA[P], pB[P];
#pragma unroll
        for (int p = 0; p < P; ++p) {
            const float* pr = proxy + p * D + lane * 8;
            pA[p] = *(const float4*)pr;
            pB[p] = *(const float4*)(pr + 4);
        }

#pragma unroll
        for (int r = 0; r < 4; ++r) {
            const int sl = wv * 4 + r;
            const int bs = bs0 + sl;
            const float* xr = x + (size_t)bs * D + lane * 8;
            float4 xa = *(const float4*)xr;
            float4 xb = *(const float4*)(xr + 4);

            float part[P];
#pragma unroll
            for (int p = 0; p < P; ++p) {
                part[p] = xa.x*pA[p].x + xa.y*pA[p].y + xa.z*pA[p].z + xa.w*pA[p].w
                        + xb.x*pB[p].x + xb.y*pB[p].y + xb.z*pB[p].z + xb.w*pB[p].w;
            }

            float a8[8];
#pragma unroll
            for (int k = 0; k < 8; ++k) {
                bool hi = lane & 1;
                float mine = hi ? part[2*k+1] : part[2*k];
                float oth  = hi ? part[2*k]   : part[2*k+1];
                a8[k] = mine + __shfl_xor(oth, 1);
            }
            float a4[4];
#pragma unroll
            for (int k = 0; k < 4; ++k) {
                bool hi = lane & 2;
                float mine = hi ? a8[2*k+1] : a8[2*k];
                float oth  = hi ? a8[2*k]   : a8[2*k+1];
                a4[k] = mine + __shfl_xor(oth, 2);
            }
            float a2[2];
#pragma unroll
            for (int k = 0; k < 2; ++k) {
                bool hi = lane & 4;
                float mine = hi ? a4[2*k+1] : a4[2*k];
                float oth  = hi ? a4[2*k]   : a4[2*k+1];
                a2[k] = mine + __shfl_xor(oth, 4);
            }
            float a1;
            {
                bool hi = lane & 8;
                float mine = hi ? a2[1] : a2[0];
                float oth  = hi ? a2[0] : a2[1];
                a1 = mine + __shfl_xor(oth, 8);
            }
            a1 += __shfl_xor(a1, 16);
            a1 += __shfl_xor(a1, 32);

            float m = a1;
#pragma unroll
            for (int off = 1; off < 16; off <<= 1) m = fmaxf(m, __shfl_xor(m, off));
            float e = __expf((a1 - m) * 0.25f);
            float den = e;
#pragma unroll
            for (int off = 1; off < 16; off <<= 1) den += __shfl_xor(den, off);

            if (lane < P) {
                float w = e / den;
                s_pr[sl][lane] = a1;
                s_w [sl][lane] = w;
                prods[(size_t)bs * P + lane] = a1;
                wgt  [(size_t)bs * P + lane] = w;
            }
        }
    }
    __syncthreads();

    // ---------------- Phase B (R13-apply-style totals)
    {
        const int d = tid;
        float xv[CL];
#pragma unroll
        for (int i = 0; i < CL; ++i) xv[i] = x[(size_t)(bs0 + i) * D + d];

        float acc[P];
#pragma unroll
        for (int p = 0; p < P; ++p) acc[p] = 0.f;

#pragma unroll
        for (int i = 0; i < CL; ++i) {
            float pr[P];
            const float4* sp = (const float4*)&s_pr[i][0];
            ((float4*)pr)[0] = sp[0];
            ((float4*)pr)[1] = sp[1];
            ((float4*)pr)[2] = sp[2];
            ((float4*)pr)[3] = sp[3];
#pragma unroll
            for (int p = 0; p < P; ++p) acc[p] = fmaf(pr[p], xv[i], acc[p]);
        }
        size_t tb = (size_t)blockIdx.x * (P * D) + d;
#pragma unroll
        for (int p = 0; p < P; ++p) T[tb + p * D] = acc[p];
    }
}

// ---------------------------------------------------------------------------
// K2: in-place exclusive prefix over chunks (R13 verbatim).
// ---------------------------------------------------------------------------
__global__ __launch_bounds__(256) void k_scan(float* __restrict__ T) {
    int t = blockIdx.x * blockDim.x + threadIdx.x;   // ((b*P+p)*D + d)
    int d = t & (D - 1);
    int p = (t >> 9) & (P - 1);
    int b = t >> 13;
    size_t base = ((size_t)b * NC * P + p) * D + d;
    float run = 0.f;
#pragma unroll 8
    for (int c = 0; c < NC; ++c) {
        size_t idx = base + (size_t)c * (P * D);
        float v = T[idx];
        T[idx] = run;
        run += v;
    }
}

// ---------------------------------------------------------------------------
// K3: apply (R13 verbatim). Block = (b,c,half), 256 threads.
// ---------------------------------------------------------------------------
__global__ __launch_bounds__(256) void k_apply(const float* __restrict__ x,
                                               const float* __restrict__ prods,
                                               const float* __restrict__ wgt,
                                               const float* __restrict__ T,
                                               float* __restrict__ out) {
    __shared__ float s_pw[2][CL][P];    // [0]=prods, [1]=wgt : 4 KiB

    int h = blockIdx.x & 1;
    int c = (blockIdx.x >> 1) & (NC - 1);
    int b = blockIdx.x >> 7;
    int d = h * 256 + threadIdx.x;
    int bs0 = b * S + c * CL;

    {
        int t = threadIdx.x;
        if (t < 128) {
            ((float4*)&s_pw[0][0][0])[t] =
                ((const float4*)(prods + (size_t)bs0 * P))[t];
        } else {
            ((float4*)&s_pw[1][0][0])[t - 128] =
                ((const float4*)(wgt + (size_t)bs0 * P))[t - 128];
        }
    }

    float xv[CL];
#pragma unroll
    for (int i = 0; i < CL; ++i) xv[i] = x[(size_t)(bs0 + i) * D + d];

    float st[P];
    size_t tb = ((size_t)(b * NC + c)) * (P * D) + d;
#pragma unroll
    for (int p = 0; p < P; ++p) st[p] = T[tb + p * D];

    __syncthreads();

#pragma unroll
    for (int i = 0; i < CL; ++i) {
        float pr[P], ww[P];
        const float4* sp = (const float4*)&s_pw[0][i][0];
        const float4* sw = (const float4*)&s_pw[1][i][0];
        ((float4*)pr)[0] = sp[0];
        ((float4*)pr)[1] = sp[1];
        ((float4*)pr)[2] = sp[2];
        ((float4*)pr)[3] = sp[3];
        ((float4*)ww)[0] = sw[0];
        ((float4*)ww)[1] = sw[1];
        ((float4*)ww)[2] = sw[2];
        ((float4*)ww)[3] = sw[3];
        float o = 0.f;
#pragma unroll
        for (int p = 0; p < P; ++p) {
            st[p] = fmaf(pr[p], xv[i], st[p]);
            o = fmaf(ww[p], st[p], o);
        }
        out[(size_t)(bs0 + i) * D + d] = o;
    }
}

extern "C" void kernel_launch(void* const* d_in, const int* in_sizes, int n_in,
                              void* d_out, int out_size, void* d_ws, size_t ws_size,
                              hipStream_t stream) {
    const float* x     = (const float*)d_in[0];
    const float* proxy = (const float*)d_in[1];
    float* out   = (float*)d_out;

    float* prods = (float*)d_ws;                 // 512 KiB
    float* wgt   = prods + (size_t)B * S * P;    // 512 KiB
    float* T     = wgt   + (size_t)B * S * P;    // 8 MiB

    k_pt   <<<B * NC,             512, 0, stream>>>(x, proxy, prods, wgt, T);
    k_scan <<<(B * P * D) / 256,  256, 0, stream>>>(T);
    k_apply<<<B * NC * 2,         256, 0, stream>>>(x, prods, wgt, T, out);
}